// Round 1
// baseline (166.289 us; speedup 1.0000x reference)
//
#include <hip/hip_runtime.h>
#include <math.h>

typedef __attribute__((ext_vector_type(8))) short short8;
typedef __attribute__((ext_vector_type(4))) float float4v;

#define D_DIM 256
#define K_EMB 1024
#define HW_SZ 1024
#define N_TOT 32768
#define SMP_B (D_DIM * HW_SZ)  // per-batch stride in X (floats)

// ---- bf16 hi/lo split helpers (RNE) ----
__device__ __forceinline__ unsigned short f2bf(float x) {
  unsigned int u = __builtin_bit_cast(unsigned int, x);
  return (unsigned short)((u + 0x7fffu + ((u >> 16) & 1u)) >> 16);
}
__device__ __forceinline__ float bf2f(unsigned short h) {
  unsigned int u = ((unsigned int)h) << 16;
  return __builtin_bit_cast(float, u);
}

// ---- async global->LDS, 16B/lane (dest = wave-uniform base + lane*16) ----
typedef const __attribute__((address_space(1))) void GV;
typedef __attribute__((address_space(3))) void LV;
__device__ __forceinline__ void async16(const void* g, void* l) {
  __builtin_amdgcn_global_load_lds((GV*)g, (LV*)l, 16, 0, 0);
}

// ---------------------------------------------------------------- prep E ----
__global__ __launch_bounds__(256) void vq_prep_e(const float* __restrict__ E,
                                                 unsigned short* __restrict__ Ehi,
                                                 unsigned short* __restrict__ Elo,
                                                 float* __restrict__ enorm) {
  int tid = blockIdx.x * 256 + threadIdx.x;  // 32768 threads, 32 per code
  int c = tid >> 5;
  int d0 = (tid & 31) * 8;
  const float* p = E + c * D_DIM + d0;
  float s = 0.f;
  short8 hv, lv;
#pragma unroll
  for (int j = 0; j < 8; ++j) {
    float x = p[j];
    s = fmaf(x, x, s);
    unsigned short h = f2bf(x);
    hv[j] = (short)h;
    lv[j] = (short)f2bf(x - bf2f(h));
  }
  *(short8*)(Ehi + c * D_DIM + d0) = hv;
  *(short8*)(Elo + c * D_DIM + d0) = lv;
#pragma unroll
  for (int off = 1; off <= 16; off <<= 1) s += __shfl_xor(s, off);
  if ((tid & 31) == 0) enorm[c] = s;
}

// ---------------------------------------------------------------- prep X ----
// Transpose+convert X [b][d][hw] fp32 -> Xt_hi/Xt_lo [n=b*1024+hw][d] bf16.
// 64d x 64hw tile per block through LDS.
__global__ __launch_bounds__(256) void vq_prep_x(const float* __restrict__ X,
                                                 unsigned short* __restrict__ Xh,
                                                 unsigned short* __restrict__ Xl) {
  __shared__ float ts[64][65];  // +1 pad: 2-way-max banks on column reads
  const int t = threadIdx.x;
  const int bi = blockIdx.x;
  const int b = bi >> 6;
  const int dt = (bi >> 4) & 3;
  const int ht = bi & 15;
  const int d0 = dt * 64;
  const int hw0 = ht * 64;

  {
    const int dl = t >> 4;
    const int hl = (t & 15) * 4;
#pragma unroll
    for (int i = 0; i < 4; ++i) {
      float4 v = *(const float4*)(X + b * SMP_B + (d0 + dl + i * 16) * HW_SZ + hw0 + hl);
      ts[dl + i * 16][hl + 0] = v.x;
      ts[dl + i * 16][hl + 1] = v.y;
      ts[dl + i * 16][hl + 2] = v.z;
      ts[dl + i * 16][hl + 3] = v.w;
    }
  }
  __syncthreads();
#pragma unroll
  for (int p = 0; p < 2; ++p) {
    const int c = t + p * 256;
    const int dch = c & 7;   // d chunk of 8
    const int nl = c >> 3;   // 0..63
    short8 hv, lv;
#pragma unroll
    for (int j = 0; j < 8; ++j) {
      float x = ts[dch * 8 + j][nl];
      unsigned short h = f2bf(x);
      hv[j] = (short)h;
      lv[j] = (short)f2bf(x - bf2f(h));
    }
    const int n = b * 1024 + hw0 + nl;
    *(short8*)(Xh + n * D_DIM + d0 + dch * 8) = hv;
    *(short8*)(Xl + n * D_DIM + d0 + dch * 8) = lv;
  }
}

// ------------------------------------------------------------------ gemm ----
// Per block: 128 codes (M) x 128 samples (N), contraction D=256 in BK=32 chunks.
// All-bf16 frags (pre-split hi/lo), 3-term MFMA; d = enorm - 2S; per-sample
// argmin over the block's 128-code stripe -> partials [8 stripes][32768].
//
// v2 structure changes vs v1 (55.4us, MfmaUtil 38.9, 4.19M LDS conflicts):
//  - T2 chunk swizzle: rows are 64B (32 shorts); fragment reads at fixed q had
//    16 lanes on 2 of 8 bank-quads (8-way conflict). Swizzle the 16B chunk
//    within each row: stored chunk = q ^ ((row>>1)&3). global_load_lds dest
//    stays LINEAR; the *global source* column is inverse-permuted per lane
//    (rule: both-sides-or-neither), and reads apply the same XOR.
//  - T3/T4 2-phase double-buffer: issue next K-step's global_load_lds before
//    computing current; raw s_barrier + counted s_waitcnt vmcnt(8) (never 0
//    mid-loop) so 8 prefetch loads stay in flight across the barrier.
//    lgkmcnt(0)+sched_barrier before the tail barrier so no wave releases the
//    buffer overwrite while its ds_reads are still in the LDS queue.
//  - T5 setprio around the MFMA cluster.
// LDS: 4 tiles x 8KB x 2 buf = 64KB + 2KB argmin scratch -> 2 blocks/CU (132KB).
__global__ __launch_bounds__(256, 2) void vq_gemm(
    const unsigned short* __restrict__ Xh, const unsigned short* __restrict__ Xl,
    const unsigned short* __restrict__ Ehi, const unsigned short* __restrict__ Elo,
    const float* __restrict__ enorm, float* __restrict__ pval, int* __restrict__ pidx) {
  __shared__ unsigned short es_hi[2][4096];  // [buf][code*32 + swz-chunk] 8KB/buf
  __shared__ unsigned short es_lo[2][4096];
  __shared__ unsigned short xs_hi[2][4096];  // [buf][smp*32 + swz-chunk]
  __shared__ unsigned short xs_lo[2][4096];
  __shared__ float rv[2][128];
  __shared__ int ri[2][128];

  const int t = threadIdx.x;
  const int i = blockIdx.x;
  // XCD-aware swizzle: all 8 code-stripes of one sample-block share i&7 -> same XCD
  const int cblk = (i >> 3) & 7;               // code stripe 0..7
  const int sblk = ((i >> 6) << 3) | (i & 7);  // sample block 0..255
  const int n0 = sblk * 128;

  const int lane = t & 63;
  const int wv = t >> 6;
  const int wm = wv >> 1;  // code half
  const int wn = wv & 1;   // sample half
  const int l15 = lane & 15;
  const int q = lane >> 4;

  float4v acc[4][4];
#pragma unroll
  for (int a = 0; a < 4; ++a)
#pragma unroll
    for (int c = 0; c < 4; ++c) acc[a][c] = {0.f, 0.f, 0.f, 0.f};

  const int srow = t >> 2;  // 0..63 (row within tile half)
  // inverse-swizzled global source column: chunk written to LDS slot (t&3)
  // must carry the data of q_data = (t&3) ^ ((row>>1)&3); (t>>3)&3 == (row>>1)&3.
  const int scol = (((t & 3) ^ ((t >> 3) & 3)) * 8);
  const unsigned short* xhb = Xh + (n0 + srow) * D_DIM + scol;
  const unsigned short* xlb = Xl + (n0 + srow) * D_DIM + scol;
  const unsigned short* ehb = Ehi + (cblk * 128 + srow) * D_DIM + scol;
  const unsigned short* elb = Elo + (cblk * 128 + srow) * D_DIM + scol;
  char* xh_b = (char*)xs_hi;
  char* xl_b = (char*)xs_lo;
  char* eh_b = (char*)es_hi;
  char* el_b = (char*)es_lo;
  const int dst0 = t * 16;

  // fragment-read column after swizzle: row = 16*m + l15 -> (row>>1)&3 = (l15>>1)&3
  const int fcol = (q ^ ((l15 >> 1) & 3)) * 8;

#define STAGE(buf, dc)                                        \
  do {                                                        \
    const int _d0 = (dc) * 32;                                \
    const int _bo = (buf) * 8192;                             \
    async16(xhb + _d0, xh_b + _bo + dst0);                    \
    async16(xhb + 64 * D_DIM + _d0, xh_b + _bo + dst0 + 4096);\
    async16(xlb + _d0, xl_b + _bo + dst0);                    \
    async16(xlb + 64 * D_DIM + _d0, xl_b + _bo + dst0 + 4096);\
    async16(ehb + _d0, eh_b + _bo + dst0);                    \
    async16(ehb + 64 * D_DIM + _d0, eh_b + _bo + dst0 + 4096);\
    async16(elb + _d0, el_b + _bo + dst0);                    \
    async16(elb + 64 * D_DIM + _d0, el_b + _bo + dst0 + 4096);\
  } while (0)

  STAGE(0, 0);  // prologue: 8 loads in flight for buffer 0

#pragma unroll
  for (int dc = 0; dc < 8; ++dc) {
    const int cur = dc & 1;
    if (dc < 7) {
      STAGE(cur ^ 1, dc + 1);  // 16 outstanding: 8 for cur + 8 prefetch
      asm volatile("s_waitcnt vmcnt(8)" ::: "memory");  // cur's 8 landed; prefetch stays in flight
    } else {
      asm volatile("s_waitcnt vmcnt(0)" ::: "memory");
    }
    __builtin_amdgcn_s_barrier();  // all 4 waves' cur-tile writes visible

    short8 ah[4], al[4], xh[4], xl[4];
#pragma unroll
    for (int mi = 0; mi < 4; ++mi) {
      int row = wm * 64 + mi * 16 + l15;
      ah[mi] = *(const short8*)&es_hi[cur][row * 32 + fcol];
      al[mi] = *(const short8*)&es_lo[cur][row * 32 + fcol];
    }
#pragma unroll
    for (int ni = 0; ni < 4; ++ni) {
      int row = wn * 64 + ni * 16 + l15;
      xh[ni] = *(const short8*)&xs_hi[cur][row * 32 + fcol];
      xl[ni] = *(const short8*)&xs_lo[cur][row * 32 + fcol];
    }
    __builtin_amdgcn_s_setprio(1);
#pragma unroll
    for (int mi = 0; mi < 4; ++mi)
#pragma unroll
      for (int ni = 0; ni < 4; ++ni)
        acc[mi][ni] = __builtin_amdgcn_mfma_f32_16x16x32_bf16(ah[mi], xh[ni], acc[mi][ni], 0, 0, 0);
#pragma unroll
    for (int mi = 0; mi < 4; ++mi)
#pragma unroll
      for (int ni = 0; ni < 4; ++ni)
        acc[mi][ni] = __builtin_amdgcn_mfma_f32_16x16x32_bf16(ah[mi], xl[ni], acc[mi][ni], 0, 0, 0);
#pragma unroll
    for (int mi = 0; mi < 4; ++mi)
#pragma unroll
      for (int ni = 0; ni < 4; ++ni)
        acc[mi][ni] = __builtin_amdgcn_mfma_f32_16x16x32_bf16(al[mi], xh[ni], acc[mi][ni], 0, 0, 0);
    __builtin_amdgcn_s_setprio(0);
    // all of this wave's ds_reads drained before releasing buffer for overwrite
    asm volatile("s_waitcnt lgkmcnt(0)" ::: "memory");
    __builtin_amdgcn_sched_barrier(0);
    __builtin_amdgcn_s_barrier();  // readers done before next iter STAGEs into cur
  }
#undef STAGE

  // ---- per-sample argmin over this block's 128 codes ----
  float en[16];
#pragma unroll
  for (int mi = 0; mi < 4; ++mi)
#pragma unroll
    for (int r = 0; r < 4; ++r)
      en[mi * 4 + r] = enorm[cblk * 128 + wm * 64 + mi * 16 + q * 4 + r];

#pragma unroll
  for (int ni = 0; ni < 4; ++ni) {
    float bv = 1e30f;
    int bc = 0;
#pragma unroll
    for (int mi = 0; mi < 4; ++mi)
#pragma unroll
      for (int r = 0; r < 4; ++r) {
        float v = fmaf(-2.f, acc[mi][ni][r], en[mi * 4 + r]);
        if (v < bv) { bv = v; bc = wm * 64 + mi * 16 + q * 4 + r; }  // ascending c
      }
#pragma unroll
    for (int off = 16; off <= 32; off <<= 1) {  // merge the 4 q-groups
      float ov = __shfl_xor(bv, off);
      int oc = __shfl_xor(bc, off);
      if (ov < bv || (ov == bv && oc < bc)) { bv = ov; bc = oc; }
    }
    if (q == 0) {
      rv[wm][wn * 64 + ni * 16 + l15] = bv;
      ri[wm][wn * 64 + ni * 16 + l15] = cblk * 128 + bc;
    }
  }
  __syncthreads();
  if (t < 128) {  // merge code halves (wm0 codes < wm1 codes: tie keeps wm0)
    float v0 = rv[0][t];
    int c0 = ri[0][t];
    float v1 = rv[1][t];
    int c1 = ri[1][t];
    if (v1 < v0) { v0 = v1; c0 = c1; }
    pval[cblk * N_TOT + sblk * 128 + t] = v0;
    pidx[cblk * N_TOT + sblk * 128 + t] = c0;
  }
}

// -------------------------------------------------------------- epilogue ----
__global__ __launch_bounds__(256) void vq_epi(
    const float* __restrict__ X, const float* __restrict__ E,
    const float* __restrict__ pval, const int* __restrict__ pidx,
    float* __restrict__ out, float* __restrict__ counts,
    float* __restrict__ lossacc) {
  __shared__ int best_idx[64];
  __shared__ float es[64][257];  // gathered best-code rows, fp32
  __shared__ float loss_part[4];
  const int t = threadIdx.x;
  const int n0 = blockIdx.x * 64;
  const int b = n0 >> 10;
  const int hw0 = n0 & 1023;

  if (t < 64) {
    int n = n0 + t;
    float bv = 1e30f;
    int bc = 0;
#pragma unroll
    for (int s = 0; s < 8; ++s) {  // ascending stripe = ascending code range
      float v = pval[s * N_TOT + n];
      int c = pidx[s * N_TOT + n];
      if (v < bv || (v == bv && c < bc)) { bv = v; bc = c; }
    }
    best_idx[t] = bc;
    atomicAdd(&counts[bc], 1.0f);
  }
  __syncthreads();

  // gather the 64 best-code E rows into LDS (coalesced 1KB/wave global reads)
#pragma unroll
  for (int i = 0; i < 16; ++i) {
    const int c = t + i * 256;
    const int r = c >> 6;           // wave-uniform row
    const int col = (c & 63) * 4;
    float4 v = *(const float4*)(E + best_idx[r] * D_DIM + col);
    es[r][col + 0] = v.x;
    es[r][col + 1] = v.y;
    es[r][col + 2] = v.z;
    es[r][col + 3] = v.w;
  }
  __syncthreads();

  const int nl4 = (t & 15) * 4;
  const int drow = t >> 4;
  const float* Xp = X + b * SMP_B + hw0 + nl4;
  float* Op = out + b * SMP_B + hw0 + nl4;
  float lsum = 0.f;
#pragma unroll 4
  for (int d = drow; d < D_DIM; d += 16) {
    float4 x = *(const float4*)(Xp + d * HW_SZ);
    float4 qv;
    qv.x = es[nl4 + 0][d];
    qv.y = es[nl4 + 1][d];
    qv.z = es[nl4 + 2][d];
    qv.w = es[nl4 + 3][d];
    *(float4*)(Op + d * HW_SZ) = qv;
    float d0 = qv.x - x.x; lsum = fmaf(d0, d0, lsum);
    float d1 = qv.y - x.y; lsum = fmaf(d1, d1, lsum);
    float d2 = qv.z - x.z; lsum = fmaf(d2, d2, lsum);
    float d3 = qv.w - x.w; lsum = fmaf(d3, d3, lsum);
  }
#pragma unroll
  for (int off = 32; off >= 1; off >>= 1) lsum += __shfl_xor(lsum, off);
  if ((t & 63) == 0) loss_part[t >> 6] = lsum;
  __syncthreads();
  if (t == 0)
    atomicAdd(lossacc, loss_part[0] + loss_part[1] + loss_part[2] + loss_part[3]);
}

// -------------------------------------------------------------- finalize ----
__global__ __launch_bounds__(256) void vq_finalize(const float* __restrict__ counts,
                                                   const float* __restrict__ lossacc,
                                                   float* __restrict__ out_tail) {
  __shared__ float part[4];
  const int t = threadIdx.x;
  float s = 0.f;
#pragma unroll
  for (int k = t; k < K_EMB; k += 256) {
    float p = counts[k] * (1.0f / 32768.0f);
    s = fmaf(p, logf(p + 1e-10f), s);
  }
#pragma unroll
  for (int off = 32; off >= 1; off >>= 1) s += __shfl_xor(s, off);
  if ((t & 63) == 0) part[t >> 6] = s;
  __syncthreads();
  if (t == 0) {
    float tot = part[0] + part[1] + part[2] + part[3];
    out_tail[0] = 1.25f * lossacc[0] * (1.0f / 8388608.0f);
    out_tail[1] = expf(-tot);
  }
}

// ---------------------------------------------------------------- launch ----
extern "C" void kernel_launch(void* const* d_in, const int* in_sizes, int n_in,
                              void* d_out, int out_size, void* d_ws, size_t ws_size,
                              hipStream_t stream) {
  const float* X = (const float*)d_in[0];  // [32,256,32,32]
  const float* E = (const float*)d_in[1];  // [1024,256]
  float* out = (float*)d_out;              // 8388608 + 2
  float* ws = (float*)d_ws;

  // d_out doubles as scratch for transposed bf16 X (exactly 8388608 floats);
  // vq_epi fully overwrites it afterwards with the real output.
  unsigned short* Xh = (unsigned short*)out;      // [32768][256] bf16
  unsigned short* Xl = Xh + N_TOT * D_DIM;        // [32768][256] bf16

  unsigned short* Ehi = (unsigned short*)ws;  // 262144 bf16 = 131072 floats
  unsigned short* Elo = Ehi + 262144;
  float* enorm = ws + 262144;                 // [1024]
  float* counts = ws + 263168;                // [1024]
  float* lossa = ws + 264192;                 // [1]
  float* pval = ws + 264256;                  // [8*32768]
  int* pidx = (int*)(ws + 264256 + 262144);   // [8*32768]

  hipMemsetAsync(counts, 0, 1088 * sizeof(float), stream);  // counts + lossa
  vq_prep_e<<<128, 256, 0, stream>>>(E, Ehi, Elo, enorm);
  vq_prep_x<<<2048, 256, 0, stream>>>(X, Xh, Xl);
  vq_gemm<<<2048, 256, 0, stream>>>(Xh, Xl, Ehi, Elo, enorm, pval, pidx);
  vq_epi<<<512, 256, 0, stream>>>(X, E, pval, pidx, out, counts, lossa);
  vq_finalize<<<1, 256, 0, stream>>>(counts, lossa, out + 8388608);
}